// Round 1
// baseline (990.563 us; speedup 1.0000x reference)
//
#include <hip/hip_runtime.h>
#include <stdint.h>

namespace {

constexpr int P   = 7;
constexpr int H   = 6;
constexpr int DH  = 30;
constexpr int DIM = 180;      // H*DH, also channel dim
constexpr int L   = 14336;
constexpr int B   = 16;
constexpr int T   = 112;      // tokens per block = 16 windows (lcm(7,16))
constexpr int NCH = L / T;    // 128 chunks per batch
constexpr int EQKV = 540;     // q(180)+k(180)+v(180)

constexpr int QKV_STRIDE = 116;  // bank-conflict-free writeback (4-row groups tile 32 banks)
constexpr int XS_STRIDE  = 194;  // 97 dwords == 1 mod 32 -> conflict-free staging writes
constexpr int OUT_STRIDE = 182;  // odd-dword stride, attn writes conflict-free

typedef __attribute__((ext_vector_type(8))) short bf16x8;
typedef __attribute__((ext_vector_type(4))) float f32x4;

union Frag {
  bf16x8 v;
  uint32_t u[4];
  unsigned short s[8];
};

__device__ __forceinline__ unsigned short f2b(float f) {
  uint32_t u = __builtin_bit_cast(uint32_t, f);
  u = (u + 0x7fffu + ((u >> 16) & 1u)) >> 16;   // RNE
  return (unsigned short)u;
}
__device__ __forceinline__ float b2f(unsigned short s) {
  uint32_t u = (uint32_t)s << 16;
  return __builtin_bit_cast(float, u);
}
__device__ __forceinline__ f32x4 zero4() { f32x4 z = {0.f, 0.f, 0.f, 0.f}; return z; }

// 8 bf16 from a 180-long fp32 weight row at cols c0..c0+7, zero-padded.
__device__ __forceinline__ bf16x8 wfrag(const float* rowp, int c0) {
  Frag f;
  if (rowp == nullptr) {
    f.u[0] = f.u[1] = f.u[2] = f.u[3] = 0u;
  } else if (c0 + 8 <= DIM) {
    float4 x = *(const float4*)(rowp + c0);
    float4 y = *(const float4*)(rowp + c0 + 4);
    f.s[0] = f2b(x.x); f.s[1] = f2b(x.y); f.s[2] = f2b(x.z); f.s[3] = f2b(x.w);
    f.s[4] = f2b(y.x); f.s[5] = f2b(y.y); f.s[6] = f2b(y.z); f.s[7] = f2b(y.w);
  } else {
#pragma unroll
    for (int j = 0; j < 8; ++j) {
      int c = c0 + j;
      f.s[j] = (c < DIM) ? f2b(rowp[c]) : (unsigned short)0;
    }
  }
  return f.v;
}

} // namespace

__global__ __launch_bounds__(256) void la_fused(
    const float* __restrict__ fmap, const float* __restrict__ Wq,
    const float* __restrict__ Wkv, const float* __restrict__ Wo,
    const float* __restrict__ bo, float* __restrict__ out) {
  // 125,280 B + 24,832 B = 150,112 B LDS (<160 KiB)
  __shared__ unsigned short qkv[EQKV * QKV_STRIDE];
  __shared__ unsigned short xs[64 * XS_STRIDE];

  const int tid  = (int)threadIdx.x;
  const int wave = tid >> 6;
  const int lane = tid & 63;
  const int l15  = lane & 15;
  const int g    = lane >> 4;

  const int bi    = (int)blockIdx.x;
  const int b     = bi >> 7;
  const int chunk = bi & 127;
  const int t0    = chunk * T;

  // ================= stage 1: qkv = [Wq;Wkv] @ x  (M=e, N=t, K=c) ==========
#pragma unroll
  for (int ph = 0; ph < 2; ++ph) {
    const int tb = ph ? 64 : 0;
    const int tn = ph ? 48 : 64;
    __syncthreads();  // protect xs from previous phase's readers
    // stage x^T tile: xs[t][c] (bf16), c in [0,192) zero-padded past 180
    for (int idx = tid; idx < 192 * tn; idx += 256) {
      const int c  = idx / tn;
      const int tt = idx - c * tn;
      float v = 0.f;
      if (c < DIM) v = fmap[(size_t)(b * DIM + c) * L + (t0 + tb + tt)];
      xs[tt * XS_STRIDE + c] = f2b(v);
    }
    __syncthreads();
    const int n0 = ph ? 4 : 0;
    const int NT = ph ? 3 : 4;  // n-tiles this phase
    const int mt0 = wave * 9;   // 36 m-tiles over padded 576 rows, 9 per wave
#pragma unroll
    for (int mg = 0; mg < 3; ++mg) {
      const int mtb = mt0 + mg * 3;
      const int nv  = (34 - mtb) < 3 ? (34 - mtb) : 3;  // tiles with any e<540
      f32x4 acc[3][4];
#pragma unroll
      for (int i = 0; i < 3; ++i)
#pragma unroll
        for (int n = 0; n < 4; ++n) acc[i][n] = zero4();
#pragma unroll
      for (int ks = 0; ks < 6; ++ks) {
        const int c0 = ks * 32 + g * 8;
        bf16x8 a[3];
#pragma unroll
        for (int i = 0; i < 3; ++i) {
          const int e = (mtb + i) * 16 + l15;
          const float* rowp = nullptr;
          if (i < nv) {
            if (e < DIM) rowp = Wq + (size_t)e * DIM;
            else if (e < EQKV) rowp = Wkv + (size_t)(e - DIM) * DIM;
          }
          a[i] = wfrag(rowp, c0);
        }
#pragma unroll
        for (int n = 0; n < NT; ++n) {
          const int trow = (n0 + n) * 16 + l15 - tb;
          Frag bf;
          const uint32_t* p = (const uint32_t*)(xs + trow * XS_STRIDE + c0);
          bf.u[0] = p[0]; bf.u[1] = p[1]; bf.u[2] = p[2]; bf.u[3] = p[3];
#pragma unroll
          for (int i = 0; i < 3; ++i) {
            if (i < nv)
              acc[i][n] = __builtin_amdgcn_mfma_f32_16x16x32_bf16(
                  a[i], bf.v, acc[i][n], 0, 0, 0);
          }
        }
      }
      // writeback: C layout col=lane&15 (=t), row=(lane>>4)*4+r (=e)
#pragma unroll
      for (int i = 0; i < 3; ++i) {
        if (i < nv) {
#pragma unroll
          for (int n = 0; n < NT; ++n) {
            const int t = (n0 + n) * 16 + l15;
#pragma unroll
            for (int r = 0; r < 4; ++r) {
              const int e = (mtb + i) * 16 + g * 4 + r;
              if (e < EQKV) qkv[e * QKV_STRIDE + t] = f2b(acc[i][n][r]);
            }
          }
        }
      }
    }
  }
  __syncthreads();

  // ================= stage 2: windowed attention (VALU) ====================
  // tasks (w,h,i): 16*6*7 = 672; each thread up to 3 tasks.
  const float scale = 0.18257418583505536f;  // 30^-0.5
  float aw[3][7];
  int tw[3], th[3], tti[3];
#pragma unroll
  for (int rr = 0; rr < 3; ++rr) {
    const int task = tid + rr * 256;
    tw[rr] = -1;
    if (task < 672) {
      const int w   = task / 42;
      const int rem = task - w * 42;
      const int h   = rem / 7;
      const int i   = rem - h * 7;
      tw[rr] = w; th[rr] = h; tti[rr] = w * 7 + i;
      float dots[7];
#pragma unroll
      for (int j = 0; j < 7; ++j) dots[j] = 0.f;
      for (int d = 0; d < 30; ++d) {
        const float qd = b2f(qkv[(h * DH + d) * QKV_STRIDE + tti[rr]]);
        const unsigned short* kr = &qkv[(DIM + h * DH + d) * QKV_STRIDE + w * 7];
#pragma unroll
        for (int j = 0; j < 7; ++j) dots[j] += qd * b2f(kr[j]);
      }
      float mx = dots[0];
#pragma unroll
      for (int j = 1; j < 7; ++j) mx = fmaxf(mx, dots[j]);
      float s = 0.f;
#pragma unroll
      for (int j = 0; j < 7; ++j) {
        const float pj = __expf(scale * (dots[j] - mx));
        aw[rr][j] = pj; s += pj;
      }
      const float inv = 1.f / s;
#pragma unroll
      for (int j = 0; j < 7; ++j) aw[rr][j] *= inv;
    }
  }
  __syncthreads();  // all dots read q before outs overwrites the q region
  // phase B: out rows -> outs[t][e] aliased over the (dead) q region.
  // outs spans bytes [0, 40768) < q region end 41760; reads only v (>=83520).
  unsigned short* outs = qkv;
#pragma unroll
  for (int rr = 0; rr < 3; ++rr) {
    if (tw[rr] >= 0) {
      const int w = tw[rr], h = th[rr], ti = tti[rr];
#pragma unroll
      for (int d = 0; d < 30; d += 2) {
        const unsigned short* v0 =
            &qkv[(2 * DIM + h * DH + d) * QKV_STRIDE + w * 7];
        const unsigned short* v1 = v0 + QKV_STRIDE;
        float o0 = 0.f, o1 = 0.f;
#pragma unroll
        for (int j = 0; j < 7; ++j) {
          const float a_ = aw[rr][j];
          o0 += a_ * b2f(v0[j]);
          o1 += a_ * b2f(v1[j]);
        }
        const uint32_t pk = (uint32_t)f2b(o0) | ((uint32_t)f2b(o1) << 16);
        *(uint32_t*)&outs[ti * OUT_STRIDE + h * DH + d] = pk;
      }
    }
  }
  __syncthreads();

  // ================= stage 3: y = Wo @ outs + bo  (M=o, N=t, K=e) ==========
  {
    const int mtb = wave * 3;  // 12 m-tiles over padded 192 o-rows
    f32x4 acc[3][7];
#pragma unroll
    for (int i = 0; i < 3; ++i)
#pragma unroll
      for (int n = 0; n < 7; ++n) acc[i][n] = zero4();
#pragma unroll
    for (int ks = 0; ks < 6; ++ks) {
      const int c0 = ks * 32 + g * 8;
      bf16x8 a[3];
#pragma unroll
      for (int i = 0; i < 3; ++i) {
        const int o = (mtb + i) * 16 + l15;
        const float* rowp = (o < DIM) ? (Wo + (size_t)o * DIM) : nullptr;
        a[i] = wfrag(rowp, c0);
      }
#pragma unroll
      for (int n = 0; n < 7; ++n) {
        const int t = n * 16 + l15;
        Frag bf;
        const uint32_t* p = (const uint32_t*)(outs + t * OUT_STRIDE + c0);
        // e>=182 spills into the next row: finite bf16 garbage * Wo-pad(0) = 0
        bf.u[0] = p[0]; bf.u[1] = p[1]; bf.u[2] = p[2]; bf.u[3] = p[3];
#pragma unroll
        for (int i = 0; i < 3; ++i)
          acc[i][n] = __builtin_amdgcn_mfma_f32_16x16x32_bf16(
              a[i], bf.v, acc[i][n], 0, 0, 0);
      }
    }
    // epilogue: bias + coalesced fp32 stores (col = t = lane&15)
#pragma unroll
    for (int i = 0; i < 3; ++i) {
#pragma unroll
      for (int r = 0; r < 4; ++r) {
        const int o = (mtb + i) * 16 + g * 4 + r;
        if (o < DIM) {
          const float bias = bo[o];
          float* orow = out + (size_t)(b * DIM + o) * L + t0;
#pragma unroll
          for (int n = 0; n < 7; ++n) orow[n * 16 + l15] = acc[i][n][r] + bias;
        }
      }
    }
  }
}

extern "C" void kernel_launch(void* const* d_in, const int* in_sizes, int n_in,
                              void* d_out, int out_size, void* d_ws, size_t ws_size,
                              hipStream_t stream) {
  const float* fmap = (const float*)d_in[0];
  const float* Wq   = (const float*)d_in[1];
  const float* Wkv  = (const float*)d_in[2];
  const float* Wo   = (const float*)d_in[3];
  const float* bo   = (const float*)d_in[4];
  float* o = (float*)d_out;
  dim3 grid(B * NCH), block(256);
  hipLaunchKernelGGL(la_fused, grid, block, 0, stream, fmap, Wq, Wkv, Wo, bo, o);
}

// Round 2
// 408.141 us; speedup vs baseline: 2.4270x; 2.4270x over previous
//
#include <hip/hip_runtime.h>
#include <stdint.h>

namespace {

constexpr int DIM  = 180;     // channels = H*DH
constexpr int LL   = 14336;
constexpr int B    = 16;
constexpr int T    = 112;     // tokens per block (16 windows)
constexpr int NCH  = 128;     // chunks per batch
constexpr int EQKV = 540;
constexpr int EPAD = 192;     // padded K / per-part channel span

constexpr int QT_STRIDE = 584;  // bf16 per token row: 3*192 + 8 pad; row=1168B (16B mult)
constexpr int XS_STRIDE = 200;  // bf16; row=400B (16B mult)

typedef __attribute__((ext_vector_type(8))) short bf16x8;
typedef __attribute__((ext_vector_type(4))) float f32x4;

union Frag { bf16x8 v; uint32_t u[4]; unsigned short s[8]; };

__device__ __forceinline__ unsigned short f2b(float f) {
  uint32_t u = __builtin_bit_cast(uint32_t, f);
  u = (u + 0x7fffu + ((u >> 16) & 1u)) >> 16;   // RNE
  return (unsigned short)u;
}
__device__ __forceinline__ float blo(uint32_t u) { return __builtin_bit_cast(float, u << 16); }
__device__ __forceinline__ float bhi(uint32_t u) { return __builtin_bit_cast(float, u & 0xffff0000u); }
__device__ __forceinline__ f32x4 zero4() { f32x4 z = {0.f,0.f,0.f,0.f}; return z; }

__device__ __forceinline__ bf16x8 zfrag() {
  Frag f; f.u[0]=f.u[1]=f.u[2]=f.u[3]=0u; return f.v;
}

} // namespace

// ---- prep: fp32 weights -> bf16, K-padded / head-padded layouts in ws ----
__global__ __launch_bounds__(1024) void la_prep(
    const float* __restrict__ Wq, const float* __restrict__ Wkv,
    const float* __restrict__ Wo, unsigned short* __restrict__ wqkv_b,
    unsigned short* __restrict__ wo_b) {
  const int idx = (int)(blockIdx.x * 1024 + threadIdx.x);
  if (idx < EQKV * EPAD) {
    const int e = idx / EPAD, c = idx - e * EPAD;
    float v = 0.f;
    if (c < DIM) v = (e < DIM) ? Wq[e * DIM + c] : Wkv[(size_t)(e - DIM) * DIM + c];
    wqkv_b[idx] = f2b(v);
  } else {
    const int k = idx - EQKV * EPAD;
    if (k < DIM * EPAD) {
      const int o = k / EPAD, cc = k - o * EPAD;
      const int h = cc >> 5, d = cc & 31;
      float v = 0.f;
      if (d < 30) v = Wo[o * DIM + h * 30 + d];
      wo_b[k] = f2b(v);
    }
  }
}

// ---- fused main kernel: 1024 threads (16 waves), T=112 tokens ----
__global__ __launch_bounds__(1024) void la_main(
    const float* __restrict__ fmap, const unsigned short* __restrict__ wqkv,
    const unsigned short* __restrict__ wo_b, const float* __restrict__ bo,
    float* __restrict__ out) {
  // 130,816 + 25,600 = 156,416 B LDS
  __shared__ unsigned short qt[T * QT_STRIDE];
  __shared__ unsigned short xs[64 * XS_STRIDE];

  const int tid  = (int)threadIdx.x;
  const int wave = tid >> 6;
  const int lane = tid & 63;
  const int l15  = lane & 15;
  const int g    = lane >> 4;

  const int bi    = (int)blockIdx.x;
  const int b     = bi >> 7;
  const int chunk = bi & 127;
  const int t0    = chunk * T;

  // ============ stage 1: qkv = Wqkv @ x, written as qt[t][part*192+h*32+d] ==
#pragma unroll
  for (int ph = 0; ph < 2; ++ph) {
    const int tb = ph ? 64 : 0;
    const int tn = ph ? 48 : 64;
    const int n0 = ph ? 4 : 0;
    const int NT = ph ? 3 : 4;
    __syncthreads();  // protect xs from previous phase readers
    // stage x tile as xs[t][c] (bf16), c zero-padded to 192
    const int nt4 = tn >> 2;
    for (int idx = tid; idx < 192 * nt4; idx += 1024) {
      const int c  = idx / nt4;
      const int t4 = idx - c * nt4;
      const int t  = t4 * 4;
      float4 v = {0.f, 0.f, 0.f, 0.f};
      if (c < DIM)
        v = *(const float4*)(fmap + (size_t)(b * DIM + c) * LL + (t0 + tb + t));
      xs[(t + 0) * XS_STRIDE + c] = f2b(v.x);
      xs[(t + 1) * XS_STRIDE + c] = f2b(v.y);
      xs[(t + 2) * XS_STRIDE + c] = f2b(v.z);
      xs[(t + 3) * XS_STRIDE + c] = f2b(v.w);
    }
    __syncthreads();
    for (int mt = wave; mt < 36; mt += 16) {
      f32x4 acc[4];
#pragma unroll
      for (int n = 0; n < 4; ++n) acc[n] = zero4();
      const int e_a = mt * 16 + l15;
#pragma unroll
      for (int ks = 0; ks < 6; ++ks) {
        const int c0 = ks * 32 + g * 8;
        const bf16x8 a = (e_a < EQKV) ? *(const bf16x8*)(wqkv + (size_t)e_a * EPAD + c0)
                                      : zfrag();
#pragma unroll
        for (int n = 0; n < 4; ++n) {
          if (n < NT) {
            const int trow = (n0 + n) * 16 + l15 - tb;
            const bf16x8 bf = *(const bf16x8*)(xs + trow * XS_STRIDE + c0);
            acc[n] = __builtin_amdgcn_mfma_f32_16x16x32_bf16(a, bf, acc[n], 0, 0, 0);
          }
        }
      }
      // writeback: C layout col=t=lane&15, row=e=(lane>>4)*4+r
#pragma unroll
      for (int n = 0; n < 4; ++n) {
        if (n < NT) {
          const int t = (n0 + n) * 16 + l15;
#pragma unroll
          for (int r = 0; r < 4; ++r) {
            const int e = mt * 16 + g * 4 + r;
            if (e < EQKV) {
              const int part = (e >= 360) ? 2 : ((e >= DIM) ? 1 : 0);
              const int rr = e - part * DIM;
              const int h = rr / 30;
              const int d = rr - h * 30;
              qt[t * QT_STRIDE + part * EPAD + h * 32 + d] = f2b(acc[n][r]);
            }
          }
        }
      }
    }
  }
  __syncthreads();

  // ============ stage 2: windowed softmax-attention (VALU, u32 LDS) =========
  // task = (w,h,i), 16*6*7 = 672 tasks; att-out overwrites own q slot.
  if (tid < 672) {
    const float scale = 0.18257418583505536f;  // 30^-0.5
    const int w   = tid / 42;
    const int rem = tid - w * 42;
    const int h   = rem / 7;
    const int i   = rem - h * 7;
    const int ti  = w * 7 + i;
    const uint32_t* qrow = (const uint32_t*)(qt + ti * QT_STRIDE + h * 32);
    const unsigned short* kbase = qt + (w * 7) * QT_STRIDE + EPAD + h * 32;
    float dots[7];
#pragma unroll
    for (int j = 0; j < 7; ++j) dots[j] = 0.f;
#pragma unroll
    for (int dp = 0; dp < 15; ++dp) {
      const uint32_t qu = qrow[dp];
      const float q0 = blo(qu), q1 = bhi(qu);
#pragma unroll
      for (int j = 0; j < 7; ++j) {
        const uint32_t ku = *(const uint32_t*)(kbase + j * QT_STRIDE + dp * 2);
        dots[j] += q0 * blo(ku);
        dots[j] += q1 * bhi(ku);
      }
    }
    float mx = dots[0];
#pragma unroll
    for (int j = 1; j < 7; ++j) mx = fmaxf(mx, dots[j]);
    float aw[7];
    float s = 0.f;
#pragma unroll
    for (int j = 0; j < 7; ++j) {
      const float pj = __expf(scale * (dots[j] - mx));
      aw[j] = pj; s += pj;
    }
    const float inv = 1.f / s;
#pragma unroll
    for (int j = 0; j < 7; ++j) aw[j] *= inv;
    const unsigned short* vbase = qt + (w * 7) * QT_STRIDE + 2 * EPAD + h * 32;
    uint32_t* orow = (uint32_t*)(qt + ti * QT_STRIDE + h * 32);
#pragma unroll
    for (int dp = 0; dp < 15; ++dp) {
      float o0 = 0.f, o1 = 0.f;
#pragma unroll
      for (int j = 0; j < 7; ++j) {
        const uint32_t vu = *(const uint32_t*)(vbase + j * QT_STRIDE + dp * 2);
        o0 += aw[j] * blo(vu);
        o1 += aw[j] * bhi(vu);
      }
      orow[dp] = (uint32_t)f2b(o0) | ((uint32_t)f2b(o1) << 16);
    }
    orow[15] = 0u;  // zero head-pad d=30,31 (K-padding for stage 3)
  }
  __syncthreads();

  // ============ stage 3: y = Wo @ att_out + bo ==============================
  for (int p = wave; p < 84; p += 16) {  // 12 m-tiles x 7 n-tiles
    const int m = p / 7;
    const int n = p - m * 7;
    f32x4 acc = zero4();
    const int o_a = m * 16 + l15;
    const int t_b = n * 16 + l15;
#pragma unroll
    for (int ks = 0; ks < 6; ++ks) {
      const int c0 = ks * 32 + g * 8;
      const bf16x8 a = (o_a < DIM) ? *(const bf16x8*)(wo_b + (size_t)o_a * EPAD + c0)
                                   : zfrag();
      const bf16x8 bf = *(const bf16x8*)(qt + t_b * QT_STRIDE + c0);
      acc = __builtin_amdgcn_mfma_f32_16x16x32_bf16(a, bf, acc, 0, 0, 0);
    }
#pragma unroll
    for (int r = 0; r < 4; ++r) {
      const int o = m * 16 + g * 4 + r;
      if (o < DIM) {
        const int t = n * 16 + l15;
        out[(size_t)(b * DIM + o) * LL + t0 + t] = acc[r] + bo[o];
      }
    }
  }
}

extern "C" void kernel_launch(void* const* d_in, const int* in_sizes, int n_in,
                              void* d_out, int out_size, void* d_ws, size_t ws_size,
                              hipStream_t stream) {
  const float* fmap = (const float*)d_in[0];
  const float* Wq   = (const float*)d_in[1];
  const float* Wkv  = (const float*)d_in[2];
  const float* Wo   = (const float*)d_in[3];
  const float* bo   = (const float*)d_in[4];
  float* o = (float*)d_out;

  unsigned short* wqkv_b = (unsigned short*)d_ws;                  // 540*192 bf16
  unsigned short* wo_b   = wqkv_b + EQKV * EPAD;                   // 180*192 bf16

  const int prep_elems = EQKV * EPAD + DIM * EPAD;                 // 138,240
  hipLaunchKernelGGL(la_prep, dim3((prep_elems + 1023) / 1024), dim3(1024), 0,
                     stream, Wq, Wkv, Wo, wqkv_b, wo_b);
  hipLaunchKernelGGL(la_main, dim3(B * NCH), dim3(1024), 0, stream,
                     fmap, wqkv_b, wo_b, bo, o);
}

// Round 5
// 401.292 us; speedup vs baseline: 2.4684x; 1.0171x over previous
//
#include <hip/hip_runtime.h>
#include <stdint.h>

namespace {

constexpr int DIM  = 180;     // channels = H*DH
constexpr int LL   = 14336;
constexpr int B    = 16;
constexpr int T    = 56;      // tokens per block (8 windows)
constexpr int NCH  = 256;     // chunks per batch
constexpr int EQKV = 540;
constexpr int EPAD = 192;     // padded K / per-part channel span

constexpr int QT_STRIDE = 584;  // u16 per token row: 3*192 + 8 pad (1168 B)
constexpr int XS_STRIDE = 200;  // u16 (400 B)
constexpr int QT_U16  = T * QT_STRIDE;        // 32704
constexpr int XS_U16  = 32 * XS_STRIDE;       // 6400
constexpr int LDS_U16 = QT_U16 + XS_U16 + 544; // 39648 u16 = 79296 B

typedef __attribute__((ext_vector_type(8))) short bf16x8;
typedef __attribute__((ext_vector_type(4))) float f32x4;

union Frag { bf16x8 v; uint32_t u[4]; unsigned short s[8]; };

__device__ __forceinline__ unsigned short f2b(float f) {
  uint32_t u = __builtin_bit_cast(uint32_t, f);
  u = (u + 0x7fffu + ((u >> 16) & 1u)) >> 16;   // RNE
  return (unsigned short)u;
}
__device__ __forceinline__ uint32_t pack2(float lo, float hi) {
  return (uint32_t)f2b(lo) | ((uint32_t)f2b(hi) << 16);
}
__device__ __forceinline__ float blo(uint32_t u) { return __builtin_bit_cast(float, u << 16); }
__device__ __forceinline__ float bhi(uint32_t u) { return __builtin_bit_cast(float, u & 0xffff0000u); }
__device__ __forceinline__ f32x4 zero4() { f32x4 z = {0.f,0.f,0.f,0.f}; return z; }
__device__ __forceinline__ bf16x8 zfrag() {
  Frag f; f.u[0]=f.u[1]=f.u[2]=f.u[3]=0u; return f.v;
}

} // namespace

// ---- prep: fp32 weights -> bf16, K-padded / head-padded layouts in ws ----
__global__ __launch_bounds__(1024) void la_prep(
    const float* __restrict__ Wq, const float* __restrict__ Wkv,
    const float* __restrict__ Wo, unsigned short* __restrict__ wqkv_b,
    unsigned short* __restrict__ wo_b) {
  const int idx = (int)(blockIdx.x * 1024 + threadIdx.x);
  if (idx < EQKV * EPAD) {
    const int e = idx / EPAD, c = idx - e * EPAD;
    float v = 0.f;
    if (c < DIM) v = (e < DIM) ? Wq[e * DIM + c] : Wkv[(size_t)(e - DIM) * DIM + c];
    wqkv_b[idx] = f2b(v);
  } else {
    const int k = idx - EQKV * EPAD;
    if (k < DIM * EPAD) {
      const int o = k / EPAD, cc = k - o * EPAD;
      const int h = cc >> 5, d = cc & 31;
      float v = 0.f;
      if (d < 30) v = Wo[o * DIM + h * 30 + d];
      wo_b[k] = f2b(v);
    }
  }
}

// ---- fused main: 512 threads (8 waves), T=56 tokens, 2 blocks/CU ----
__global__ __launch_bounds__(512, 4) void la_main(
    const float* __restrict__ fmap, const unsigned short* __restrict__ wqkv,
    const unsigned short* __restrict__ wo_b, const float* __restrict__ bo,
    float* __restrict__ out) {
  __shared__ unsigned short lds[LDS_U16];
  unsigned short* qt  = lds;               // [56][584]
  unsigned short* xs  = lds + QT_U16;      // [32][200]
  unsigned short* lut = xs + XS_U16;       // [544]

  const int tid  = (int)threadIdx.x;
  const int wave = tid >> 6;
  const int lane = tid & 63;
  const int l15  = lane & 15;
  const int g    = lane >> 4;

  const int bi    = (int)blockIdx.x;
  const int b     = bi >> 8;
  const int chunk = bi & 255;
  const int t0    = chunk * T;

  // one-time: e -> qt column LUT (strided: 512 threads < 540 entries)
  for (int e = tid; e < EQKV; e += 512) {
    const int part = (e >= 360) ? 2 : ((e >= DIM) ? 1 : 0);
    const int rr = e - part * DIM;
    const int h = rr / 30;
    const int d = rr - h * 30;
    lut[e] = (unsigned short)(part * EPAD + h * 32 + d);
  }

  // ============ stage 1: qkv = Wqkv @ x -> qt[t][part*192+h*32+d] ===========
#pragma unroll
  for (int ph = 0; ph < 2; ++ph) {
    const int tb = ph * 32;
    __syncthreads();  // xs reuse (and lut visibility on ph0)
    // stage 32 tokens as xs[t_local][c], zero-padded c>=180 / t>=56
#pragma unroll
    for (int it = 0; it < 3; ++it) {
      const int idx = tid + it * 512;      // 192 c x 8 quad-token groups
      const int c  = idx >> 3;
      const int tl = (idx & 7) * 4;
      float4 v = {0.f, 0.f, 0.f, 0.f};
      if (c < DIM && (tb + tl) < T)
        v = *(const float4*)(fmap + (size_t)(b * DIM + c) * LL + t0 + tb + tl);
      unsigned short* xr = xs + tl * XS_STRIDE + c;
      xr[0 * XS_STRIDE] = f2b(v.x);
      xr[1 * XS_STRIDE] = f2b(v.y);
      xr[2 * XS_STRIDE] = f2b(v.z);
      xr[3 * XS_STRIDE] = f2b(v.w);
    }
    __syncthreads();
    for (int mt = wave; mt < 36; mt += 8) {
      const int e_a = mt * 16 + l15;
      f32x4 acc0 = zero4(), acc1 = zero4();
#pragma unroll
      for (int ks = 0; ks < 6; ++ks) {
        const int c0 = ks * 32 + g * 8;
        const bf16x8 a = (e_a < EQKV)
            ? *(const bf16x8*)(wqkv + (size_t)e_a * EPAD + c0) : zfrag();
        const bf16x8 b0 = *(const bf16x8*)(xs + l15 * XS_STRIDE + c0);
        const bf16x8 b1 = *(const bf16x8*)(xs + (16 + l15) * XS_STRIDE + c0);
        acc0 = __builtin_amdgcn_mfma_f32_16x16x32_bf16(a, b0, acc0, 0, 0, 0);
        acc1 = __builtin_amdgcn_mfma_f32_16x16x32_bf16(a, b1, acc1, 0, 0, 0);
      }
      // writeback: C layout col=t=lane&15, row=e=(lane>>4)*4+r
      const int e0 = mt * 16 + g * 4;
#pragma unroll
      for (int nt = 0; nt < 2; ++nt) {
        const f32x4 A = nt ? acc1 : acc0;
        const int t = tb + nt * 16 + l15;
        if (t < T) {
          unsigned short* qrow = qt + t * QT_STRIDE;
          if (e0 + 0 < EQKV) qrow[lut[e0 + 0]] = f2b(A[0]);
          if (e0 + 1 < EQKV) qrow[lut[e0 + 1]] = f2b(A[1]);
          if (e0 + 2 < EQKV) qrow[lut[e0 + 2]] = f2b(A[2]);
          if (e0 + 3 < EQKV) qrow[lut[e0 + 3]] = f2b(A[3]);
        }
      }
    }
  }
  __syncthreads();

  // ============ stage 2: windowed softmax-attention (8 windows) =============
  if (tid < 336) {  // (w,h,i): 8*6*7
    const float scale = 0.18257418583505536f;  // 30^-0.5
    const int w   = tid / 42;
    const int rem = tid - w * 42;
    const int h   = rem / 7;
    const int i   = rem - h * 7;
    const int ti  = w * 7 + i;
    const uint32_t* qrow = (const uint32_t*)(qt + ti * QT_STRIDE + h * 32);
    const unsigned short* kbase = qt + (w * 7) * QT_STRIDE + EPAD + h * 32;
    float dots[7];
#pragma unroll
    for (int j = 0; j < 7; ++j) dots[j] = 0.f;
#pragma unroll
    for (int dp = 0; dp < 15; ++dp) {
      const uint32_t qu = qrow[dp];
      const float q0 = blo(qu), q1 = bhi(qu);
#pragma unroll
      for (int j = 0; j < 7; ++j) {
        const uint32_t ku = *(const uint32_t*)(kbase + j * QT_STRIDE + dp * 2);
        dots[j] += q0 * blo(ku);
        dots[j] += q1 * bhi(ku);
      }
    }
    float mx = dots[0];
#pragma unroll
    for (int j = 1; j < 7; ++j) mx = fmaxf(mx, dots[j]);
    float aw[7];
    float s = 0.f;
#pragma unroll
    for (int j = 0; j < 7; ++j) {
      const float pj = __expf(scale * (dots[j] - mx));
      aw[j] = pj; s += pj;
    }
    const float inv = 1.f / s;
#pragma unroll
    for (int j = 0; j < 7; ++j) aw[j] *= inv;
    const unsigned short* vbase = qt + (w * 7) * QT_STRIDE + 2 * EPAD + h * 32;
    uint32_t* orow = (uint32_t*)(qt + ti * QT_STRIDE + h * 32);
#pragma unroll
    for (int dp = 0; dp < 15; ++dp) {
      float o0 = 0.f, o1 = 0.f;
#pragma unroll
      for (int j = 0; j < 7; ++j) {
        const uint32_t vu = *(const uint32_t*)(vbase + j * QT_STRIDE + dp * 2);
        o0 += aw[j] * blo(vu);
        o1 += aw[j] * bhi(vu);
      }
      orow[dp] = pack2(o0, o1);
    }
    orow[15] = 0u;  // zero head-pad d=30,31 (K-padding for stage 3)
  }
  __syncthreads();

  // ============ stage 3: y = Wo @ att_out + bo ==============================
  for (int p = wave; p < 48; p += 8) {  // 12 m-tiles x 4 n-tiles
    const int m = p >> 2;
    const int n = p & 3;
    const int o_a  = m * 16 + l15;
    const int tcol = n * 16 + l15;
    const int trd  = (tcol < T) ? tcol : (T - 1);  // clamp: read valid row,
    f32x4 acc = zero4();                           // result discarded below
#pragma unroll
    for (int ks = 0; ks < 6; ++ks) {
      const int c0 = ks * 32 + g * 8;
      const bf16x8 a = (o_a < DIM)
          ? *(const bf16x8*)(wo_b + (size_t)o_a * EPAD + c0) : zfrag();
      const bf16x8 bf = *(const bf16x8*)(qt + trd * QT_STRIDE + c0);
      acc = __builtin_amdgcn_mfma_f32_16x16x32_bf16(a, bf, acc, 0, 0, 0);
    }
    if (tcol < T) {
#pragma unroll
      for (int r = 0; r < 4; ++r) {
        const int o = m * 16 + g * 4 + r;
        if (o < DIM)
          out[(size_t)(b * DIM + o) * LL + t0 + tcol] = acc[r] + bo[o];
      }
    }
  }
}

extern "C" void kernel_launch(void* const* d_in, const int* in_sizes, int n_in,
                              void* d_out, int out_size, void* d_ws, size_t ws_size,
                              hipStream_t stream) {
  const float* fmap = (const float*)d_in[0];
  const float* Wq   = (const float*)d_in[1];
  const float* Wkv  = (const float*)d_in[2];
  const float* Wo   = (const float*)d_in[3];
  const float* bo   = (const float*)d_in[4];
  float* o = (float*)d_out;

  unsigned short* wqkv_b = (unsigned short*)d_ws;                  // 540*192 bf16
  unsigned short* wo_b   = wqkv_b + EQKV * EPAD;                   // 180*192 bf16

  const int prep_elems = EQKV * EPAD + DIM * EPAD;                 // 138,240
  hipLaunchKernelGGL(la_prep, dim3((prep_elems + 1023) / 1024), dim3(1024), 0,
                     stream, Wq, Wkv, Wo, wqkv_b, wo_b);
  hipLaunchKernelGGL(la_main, dim3(B * NCH), dim3(512), 0, stream,
                     fmap, wqkv_b, wo_b, bo, o);
}